// Round 1
// baseline (4629.942 us; speedup 1.0000x reference)
//
#include <hip/hip_runtime.h>

#define Nn 4096
#define Dd 512
#define Ee 65536
#define HOPS 10
#define TPB 512
#define RPT (Nn / TPB)  // 8 rows per thread
#define CT 4            // columns per block

// ---------------- xw = x*w (per column), sq[i] = sum_d w_d * x[i,d]^2 ----------------
__global__ __launch_bounds__(256) void k_xw_sq(const float* __restrict__ x,
                                               const float* __restrict__ w,
                                               float* __restrict__ xw,
                                               float* __restrict__ sq) {
  int row = blockIdx.x;
  int tid = threadIdx.x;
  const float* xr = x + (size_t)row * Dd;
  float* xwr = xw + (size_t)row * Dd;
  float partial = 0.f;
  for (int d = tid; d < Dd; d += 256) {
    float xv = xr[d];
    float xwv = xv * w[d];
    xwr[d] = xwv;
    partial += xwv * xv;
  }
  for (int off = 32; off >= 1; off >>= 1) partial += __shfl_down(partial, off, 64);
  __shared__ float red[4];
  int wv = tid >> 6, ln = tid & 63;
  if (ln == 0) red[wv] = partial;
  __syncthreads();
  if (tid == 0) sq[row] = red[0] + red[1] + red[2] + red[3];
}

// ---------------- K = sq_i + sq_j - 2 * xw @ x^T ; diag -> 1  (fp32, NT GEMM) ----------------
__global__ __launch_bounds__(256) void k_gemm(const float* __restrict__ A,  // xw [N,D]
                                              const float* __restrict__ B,  // x  [N,D]
                                              const float* __restrict__ sq,
                                              float* __restrict__ C) {
  __shared__ float As[8][128];
  __shared__ float Bs[8][128];
  int i0 = blockIdx.y * 128, j0 = blockIdx.x * 128;
  int tid = threadIdx.x;
  int ty = tid >> 4, tx = tid & 15;
  int lr = tid >> 1, lk = (tid & 1) * 4;
  float acc[8][8];
#pragma unroll
  for (int a = 0; a < 8; a++)
#pragma unroll
    for (int b = 0; b < 8; b++) acc[a][b] = 0.f;

  for (int k0 = 0; k0 < Dd; k0 += 8) {
    float4 av4 = *(const float4*)&A[(size_t)(i0 + lr) * Dd + k0 + lk];
    float4 bv4 = *(const float4*)&B[(size_t)(j0 + lr) * Dd + k0 + lk];
    As[lk + 0][lr] = av4.x; As[lk + 1][lr] = av4.y; As[lk + 2][lr] = av4.z; As[lk + 3][lr] = av4.w;
    Bs[lk + 0][lr] = bv4.x; Bs[lk + 1][lr] = bv4.y; Bs[lk + 2][lr] = bv4.z; Bs[lk + 3][lr] = bv4.w;
    __syncthreads();
#pragma unroll
    for (int kk = 0; kk < 8; kk++) {
      float av[8], bv[8];
      *(float4*)&av[0] = *(const float4*)&As[kk][ty * 8];
      *(float4*)&av[4] = *(const float4*)&As[kk][ty * 8 + 4];
      *(float4*)&bv[0] = *(const float4*)&Bs[kk][tx * 8];
      *(float4*)&bv[4] = *(const float4*)&Bs[kk][tx * 8 + 4];
#pragma unroll
      for (int a = 0; a < 8; a++)
#pragma unroll
        for (int b = 0; b < 8; b++) acc[a][b] += av[a] * bv[b];
    }
    __syncthreads();
  }
#pragma unroll
  for (int a = 0; a < 8; a++) {
    int gi = i0 + ty * 8 + a;
    float sqi = sq[gi];
    float outv[8];
#pragma unroll
    for (int b = 0; b < 8; b++) {
      int gj = j0 + tx * 8 + b;
      float v = sqi + sq[gj] - 2.f * acc[a][b];
      outv[b] = (gi == gj) ? 1.0f : v;
    }
    float* Cr = &C[(size_t)gi * Nn + j0 + tx * 8];
    *(float4*)&Cr[0] = *(float4*)&outv[0];
    *(float4*)&Cr[4] = *(float4*)&outv[4];
  }
}

// ---------------- degree counting ----------------
__global__ void k_count(const int* __restrict__ src, const int* __restrict__ dst,
                        int* __restrict__ degi, int* __restrict__ degrow) {
  int e = blockIdx.x * blockDim.x + threadIdx.x;
  if (e < Ee) {
    atomicAdd(&degi[dst[e]], 1);
    atomicAdd(&degrow[src[e]], 1);
  }
}

// ---------------- row_ptr = exclusive scan of (in-deg + self-loop); dis = deg^-0.5 ----------------
__global__ __launch_bounds__(1024) void k_scan(const int* __restrict__ degi,
                                               int* __restrict__ rowptr,
                                               int* __restrict__ fill,
                                               float* __restrict__ dis) {
  __shared__ int part[1024];
  int t = threadIdx.x;
  int base = t * 4;
  int c[4];
  int s = 0;
#pragma unroll
  for (int j = 0; j < 4; j++) {
    c[j] = degi[base + j] + 1;  // +1 self-loop
    s += c[j];
    dis[base + j] = rsqrtf((float)c[j]);
  }
  part[t] = s;
  __syncthreads();
  for (int off = 1; off < 1024; off <<= 1) {
    int v = (t >= off) ? part[t - off] : 0;
    __syncthreads();
    part[t] += v;
    __syncthreads();
  }
  int excl = part[t] - s;
#pragma unroll
  for (int j = 0; j < 4; j++) {
    rowptr[base + j] = excl;
    fill[base + j] = excl;
    excl += c[j];
  }
  if (t == 1023) rowptr[Nn] = excl;
}

// ---------------- CSR fill: edges + self-loops, norm = dis[s]*dis[d] ----------------
__global__ void k_fill(const int* __restrict__ src, const int* __restrict__ dst,
                       const float* __restrict__ dis, int* __restrict__ fill,
                       int2* __restrict__ colval) {
  int i = blockIdx.x * blockDim.x + threadIdx.x;
  if (i < Ee) {
    int s = src[i], d = dst[i];
    int p = atomicAdd(&fill[d], 1);
    colval[p] = make_int2(s, __float_as_int(dis[s] * dis[d]));
  } else if (i < Ee + Nn) {
    int v = i - Ee;
    int p = atomicAdd(&fill[v], 1);
    colval[p] = make_int2(v, __float_as_int(dis[v] * dis[v]));
  }
}

// ---------------- fused 10-hop APPNP on a 4-column slab; h resident in LDS ----------------
// Input pattern (both passes): x0_tile[r][c] = xsrc[(j0+c)*Nn + r]   (coalesced scalar loads)
//   pass 1: xsrc = K (symmetric, so this equals K[r][j0+c])
//   pass 2: xsrc = kgg1 row-major => tile = kgg1^T[r][j0+c]  (the reference's transpose)
// Output:
//   PASS 1: dst[r*Nn + j0 .. +3] = kgg1 row-major (float4, strided across rows)
//   PASS 2: dst[(j0+c)*Nn + r]   = kgg2^T with diagonal scaled by 1/(deg_row+1) (coalesced)
template <int PASS>
__global__ __launch_bounds__(TPB, 4) void k_appnp(const float* __restrict__ xsrc,
                                                  float* __restrict__ dst,
                                                  const int* __restrict__ rowptr,
                                                  const int2* __restrict__ colval,
                                                  const int* __restrict__ degrow) {
  extern __shared__ float4 h4[];  // Nn entries = 64 KB
  int j0 = blockIdx.x * CT;
  int tid = threadIdx.x;
  float4 x0r[RPT];
  int rp0[RPT], rp1[RPT];
#pragma unroll
  for (int rr = 0; rr < RPT; rr++) {
    int r = tid + rr * TPB;
    float4 v;
    v.x = xsrc[(size_t)(j0 + 0) * Nn + r];
    v.y = xsrc[(size_t)(j0 + 1) * Nn + r];
    v.z = xsrc[(size_t)(j0 + 2) * Nn + r];
    v.w = xsrc[(size_t)(j0 + 3) * Nn + r];
    x0r[rr] = v;
    h4[r] = v;
    rp0[rr] = rowptr[r];
    rp1[rr] = rowptr[r + 1];
  }
  __syncthreads();
  float4 res[RPT];
  for (int it = 0; it < HOPS; it++) {
#pragma unroll
    for (int rr = 0; rr < RPT; rr++) {
      float4 acc = make_float4(0.f, 0.f, 0.f, 0.f);
      for (int p = rp0[rr]; p < rp1[rr]; p++) {
        int2 cv = colval[p];
        float vv = __int_as_float(cv.y);
        float4 hu = h4[cv.x];
        acc.x += vv * hu.x;
        acc.y += vv * hu.y;
        acc.z += vv * hu.z;
        acc.w += vv * hu.w;
      }
      float4 x0v = x0r[rr];
      res[rr].x = 0.5f * acc.x + 0.5f * x0v.x;
      res[rr].y = 0.5f * acc.y + 0.5f * x0v.y;
      res[rr].z = 0.5f * acc.z + 0.5f * x0v.z;
      res[rr].w = 0.5f * acc.w + 0.5f * x0v.w;
    }
    if (it < HOPS - 1) {
      __syncthreads();
#pragma unroll
      for (int rr = 0; rr < RPT; rr++) h4[tid + rr * TPB] = res[rr];
      __syncthreads();
    }
  }
  if (PASS == 1) {
#pragma unroll
    for (int rr = 0; rr < RPT; rr++) {
      int r = tid + rr * TPB;
      *(float4*)&dst[(size_t)r * Nn + j0] = res[rr];
    }
  } else {
#pragma unroll
    for (int rr = 0; rr < RPT; rr++) {
      int r = tid + rr * TPB;
      float vals[4] = {res[rr].x, res[rr].y, res[rr].z, res[rr].w};
#pragma unroll
      for (int c = 0; c < 4; c++) {
        float v = vals[c];
        if (r == j0 + c) v *= 1.0f / ((float)degrow[r] + 1.0f);
        dst[(size_t)(j0 + c) * Nn + r] = v;
      }
    }
  }
}

extern "C" void kernel_launch(void* const* d_in, const int* in_sizes, int n_in,
                              void* d_out, int out_size, void* d_ws, size_t ws_size,
                              hipStream_t stream) {
  const float* x = (const float*)d_in[0];   // [N,D]
  const float* w = (const float*)d_in[1];   // [D]
  const int* ei = (const int*)d_in[2];      // [2,E]
  const int* src = ei;
  const int* dstv = ei + Ee;
  float* out = (float*)d_out;

  // workspace layout (~73 MB)
  float* W1 = (float*)d_ws;                  // Nn*Nn : K, then final (kgg2^T scaled)
  float* xw = W1 + (size_t)Nn * Nn;          // Nn*Dd
  float* sq = xw + (size_t)Nn * Dd;          // Nn
  float* dis = sq + Nn;                      // Nn
  int2* colval = (int2*)(dis + Nn);          // Ee+Nn
  int* degi = (int*)(colval + (Ee + Nn));    // Nn
  int* degrow = degi + Nn;                   // Nn
  int* rowptr = degrow + Nn;                 // Nn+1
  int* fill = rowptr + (Nn + 1);             // Nn

  hipMemsetAsync(degi, 0, sizeof(int) * 2 * Nn, stream);
  k_xw_sq<<<Nn, 256, 0, stream>>>(x, w, xw, sq);
  k_gemm<<<dim3(Nn / 128, Nn / 128), 256, 0, stream>>>(xw, x, sq, W1);
  k_count<<<Ee / 256, 256, 0, stream>>>(src, dstv, degi, degrow);
  k_scan<<<1, 1024, 0, stream>>>(degi, rowptr, fill, dis);
  k_fill<<<(Ee + Nn + 255) / 256, 256, 0, stream>>>(src, dstv, dis, fill, colval);

  // pass 1: kgg1 = APPNP(K) ; K symmetric so transposed read == direct read
  k_appnp<1><<<Nn / CT, TPB, Nn * sizeof(float4), stream>>>(W1, out, rowptr, colval, nullptr);
  // pass 2: kgg2 = APPNP(kgg1^T) ; writes kgg2^T with diag/(deg_row+1) into W1
  k_appnp<2><<<Nn / CT, TPB, Nn * sizeof(float4), stream>>>(out, W1, rowptr, colval, degrow);

  hipMemcpyAsync(out, W1, (size_t)Nn * Nn * sizeof(float), hipMemcpyDeviceToDevice, stream);
}

// Round 2
// 1775.753 us; speedup vs baseline: 2.6073x; 2.6073x over previous
//
#include <hip/hip_runtime.h>

#define Nn 4096
#define Dd 512
#define Ee 65536
#define HOPS 10
#define TPB 512
#define RPT (Nn / TPB)  // 8 rows per thread
#define CT 4            // columns per block
#define WCAP 64         // ELL slot capacity (max in-degree+1; Poisson(16) max ~38)

// ---------------- sq[i] = sum_d w_d * x[i,d]^2 ----------------
__global__ __launch_bounds__(256) void k_sq(const float* __restrict__ x,
                                            const float* __restrict__ w,
                                            float* __restrict__ sq) {
  int row = blockIdx.x;
  int tid = threadIdx.x;
  const float* xr = x + (size_t)row * Dd;
  float partial = 0.f;
  for (int d = tid; d < Dd; d += 256) {
    float xv = xr[d];
    partial += xv * xv * w[d];
  }
  for (int off = 32; off >= 1; off >>= 1) partial += __shfl_down(partial, off, 64);
  __shared__ float red[4];
  int wv = tid >> 6, ln = tid & 63;
  if (ln == 0) red[wv] = partial;
  __syncthreads();
  if (tid == 0) sq[row] = red[0] + red[1] + red[2] + red[3];
}

// ---------------- K = sq_i + sq_j - 2 * (x*w) @ x^T ; diag -> 1 ----------------
__global__ __launch_bounds__(256) void k_gemm(const float* __restrict__ X,
                                              const float* __restrict__ w,
                                              const float* __restrict__ sq,
                                              float* __restrict__ C) {
  __shared__ float As[8][128];
  __shared__ float Bs[8][128];
  int i0 = blockIdx.y * 128, j0 = blockIdx.x * 128;
  int tid = threadIdx.x;
  int ty = tid >> 4, tx = tid & 15;
  int lr = tid >> 1, lk = (tid & 1) * 4;
  float acc[8][8];
#pragma unroll
  for (int a = 0; a < 8; a++)
#pragma unroll
    for (int b = 0; b < 8; b++) acc[a][b] = 0.f;

  for (int k0 = 0; k0 < Dd; k0 += 8) {
    float4 wv4 = *(const float4*)&w[k0 + lk];
    float4 av4 = *(const float4*)&X[(size_t)(i0 + lr) * Dd + k0 + lk];
    float4 bv4 = *(const float4*)&X[(size_t)(j0 + lr) * Dd + k0 + lk];
    As[lk + 0][lr] = av4.x * wv4.x; As[lk + 1][lr] = av4.y * wv4.y;
    As[lk + 2][lr] = av4.z * wv4.z; As[lk + 3][lr] = av4.w * wv4.w;
    Bs[lk + 0][lr] = bv4.x; Bs[lk + 1][lr] = bv4.y; Bs[lk + 2][lr] = bv4.z; Bs[lk + 3][lr] = bv4.w;
    __syncthreads();
#pragma unroll
    for (int kk = 0; kk < 8; kk++) {
      float av[8], bv[8];
      *(float4*)&av[0] = *(const float4*)&As[kk][ty * 8];
      *(float4*)&av[4] = *(const float4*)&As[kk][ty * 8 + 4];
      *(float4*)&bv[0] = *(const float4*)&Bs[kk][tx * 8];
      *(float4*)&bv[4] = *(const float4*)&Bs[kk][tx * 8 + 4];
#pragma unroll
      for (int a = 0; a < 8; a++)
#pragma unroll
        for (int b = 0; b < 8; b++) acc[a][b] += av[a] * bv[b];
    }
    __syncthreads();
  }
#pragma unroll
  for (int a = 0; a < 8; a++) {
    int gi = i0 + ty * 8 + a;
    float sqi = sq[gi];
    float outv[8];
#pragma unroll
    for (int b = 0; b < 8; b++) {
      int gj = j0 + tx * 8 + b;
      float v = sqi + sq[gj] - 2.f * acc[a][b];
      outv[b] = (gi == gj) ? 1.0f : v;
    }
    float* Cr = &C[(size_t)gi * Nn + j0 + tx * 8];
    *(float4*)&Cr[0] = *(float4*)&outv[0];
    *(float4*)&Cr[4] = *(float4*)&outv[4];
  }
}

// ---------------- degree counting ----------------
__global__ void k_count(const int* __restrict__ src, const int* __restrict__ dst,
                        int* __restrict__ degi, int* __restrict__ degrow) {
  int e = blockIdx.x * blockDim.x + threadIdx.x;
  if (e < Ee) {
    atomicAdd(&degi[dst[e]], 1);
    atomicAdd(&degrow[src[e]], 1);
  }
}

// ---------------- dis = (deg_in+1)^-0.5 ; wmax = max(deg_in+1) ----------------
__global__ void k_dis(const int* __restrict__ degi, float* __restrict__ dis,
                      int* __restrict__ wmax) {
  int i = blockIdx.x * 256 + threadIdx.x;
  int d = degi[i] + 1;
  dis[i] = rsqrtf((float)d);
  int m = d;
  for (int off = 32; off >= 1; off >>= 1) m = max(m, __shfl_down(m, off, 64));
  if ((threadIdx.x & 63) == 0) atomicMax(wmax, m);
}

// ---------------- ELL fill (slot-major): ell[slot*Nn + dstrow] = {srccol, norm} ----------------
// ELL pre-zeroed: dummy slots are {col=0, val=0} -> broadcast LDS read + FMA by 0.
__global__ void k_fill_ell(const int* __restrict__ src, const int* __restrict__ dst,
                           const float* __restrict__ dis, int* __restrict__ slot,
                           int2* __restrict__ ell) {
  int i = blockIdx.x * blockDim.x + threadIdx.x;
  if (i < Ee) {
    int s = src[i], d = dst[i];
    int p = atomicAdd(&slot[d], 1);
    if (p < WCAP) ell[(size_t)p * Nn + d] = make_int2(s, __float_as_int(dis[s] * dis[d]));
  } else if (i < Ee + Nn) {
    int v = i - Ee;
    int p = atomicAdd(&slot[v], 1);
    if (p < WCAP) ell[(size_t)p * Nn + v] = make_int2(v, __float_as_int(dis[v] * dis[v]));
  }
}

// ---------------- fused 10-hop APPNP on a 4-column slab; h resident in LDS ----------------
// ELL slot-major: per slot, lane r loads ell[s*Nn+r] coalesced; 8 independent
// gather chains per thread + slot double-buffer -> latency hidden, LDS-issue bound.
// PASS 1: xsrc=K (symmetric -> column read == row read), writes kgg1 row-major.
// PASS 2: xsrc=dst=kgg1 row-major IN PLACE: block reads only rows j0..j0+3 (at
//         start, into regs/LDS) and writes only rows j0..j0+3 (at end) -> safe.
template <int PASS>
__global__ __launch_bounds__(TPB, 4) void k_appnp(const float* __restrict__ xsrc,
                                                  float* __restrict__ dst,
                                                  const int2* __restrict__ ell,
                                                  const int* __restrict__ wmaxp,
                                                  const int* __restrict__ degrow) {
  extern __shared__ float4 h4[];  // Nn entries = 64 KB
  const int W = *wmaxp;
  int j0 = blockIdx.x * CT;
  int tid = threadIdx.x;
  float4 x0r[RPT];
#pragma unroll
  for (int rr = 0; rr < RPT; rr++) {
    int r = tid + rr * TPB;
    float4 v;
    v.x = xsrc[(size_t)(j0 + 0) * Nn + r];
    v.y = xsrc[(size_t)(j0 + 1) * Nn + r];
    v.z = xsrc[(size_t)(j0 + 2) * Nn + r];
    v.w = xsrc[(size_t)(j0 + 3) * Nn + r];
    x0r[rr] = v;
    h4[r] = v;
  }
  __syncthreads();
  float4 acc[RPT];
  for (int it = 0; it < HOPS; it++) {
    int2 cur[RPT];
#pragma unroll
    for (int rr = 0; rr < RPT; rr++) cur[rr] = ell[tid + rr * TPB];  // slot 0 (always exists)
#pragma unroll
    for (int rr = 0; rr < RPT; rr++) acc[rr] = x0r[rr];  // alpha*x0 folded: res = 0.5*(x0 + sum)
    for (int s = 0; s < W; s++) {
      int sn = (s + 1 < W) ? s + 1 : s;
      int2 nxt[RPT];
#pragma unroll
      for (int rr = 0; rr < RPT; rr++) nxt[rr] = ell[(size_t)sn * Nn + tid + rr * TPB];
#pragma unroll
      for (int rr = 0; rr < RPT; rr++) {
        float vv = __int_as_float(cur[rr].y);
        float4 hu = h4[cur[rr].x];
        acc[rr].x = fmaf(vv, hu.x, acc[rr].x);
        acc[rr].y = fmaf(vv, hu.y, acc[rr].y);
        acc[rr].z = fmaf(vv, hu.z, acc[rr].z);
        acc[rr].w = fmaf(vv, hu.w, acc[rr].w);
      }
#pragma unroll
      for (int rr = 0; rr < RPT; rr++) cur[rr] = nxt[rr];
    }
#pragma unroll
    for (int rr = 0; rr < RPT; rr++) {
      acc[rr].x *= 0.5f; acc[rr].y *= 0.5f; acc[rr].z *= 0.5f; acc[rr].w *= 0.5f;
    }
    if (it < HOPS - 1) {
      __syncthreads();
#pragma unroll
      for (int rr = 0; rr < RPT; rr++) h4[tid + rr * TPB] = acc[rr];
      __syncthreads();
    }
  }
  if (PASS == 1) {
#pragma unroll
    for (int rr = 0; rr < RPT; rr++) {
      int r = tid + rr * TPB;
      *(float4*)&dst[(size_t)r * Nn + j0] = acc[rr];
    }
  } else {
#pragma unroll
    for (int rr = 0; rr < RPT; rr++) {
      int r = tid + rr * TPB;
      float vals[4] = {acc[rr].x, acc[rr].y, acc[rr].z, acc[rr].w};
#pragma unroll
      for (int c = 0; c < 4; c++) {
        float v = vals[c];
        if (r == j0 + c) v *= 1.0f / ((float)degrow[r] + 1.0f);
        dst[(size_t)(j0 + c) * Nn + r] = v;
      }
    }
  }
}

extern "C" void kernel_launch(void* const* d_in, const int* in_sizes, int n_in,
                              void* d_out, int out_size, void* d_ws, size_t ws_size,
                              hipStream_t stream) {
  const float* x = (const float*)d_in[0];  // [N,D]
  const float* w = (const float*)d_in[1];  // [D]
  const int* ei = (const int*)d_in[2];     // [2,E]
  const int* src = ei;
  const int* dstv = ei + Ee;
  float* out = (float*)d_out;

  // workspace layout (~67 MB)
  float* W1 = (float*)d_ws;               // Nn*Nn : K
  float* sq = W1 + (size_t)Nn * Nn;       // Nn
  float* dis = sq + Nn;                   // Nn
  int2* ell = (int2*)(dis + Nn);          // WCAP*Nn (2 MB)
  int* degi = (int*)(ell + (size_t)WCAP * Nn);  // Nn
  int* degrow = degi + Nn;                // Nn
  int* slotcnt = degrow + Nn;             // Nn
  int* wmax = slotcnt + Nn;               // 1

  hipMemsetAsync(ell, 0, (size_t)WCAP * Nn * sizeof(int2), stream);
  hipMemsetAsync(degi, 0, sizeof(int) * (3 * Nn + 1), stream);

  k_sq<<<Nn, 256, 0, stream>>>(x, w, sq);
  k_gemm<<<dim3(Nn / 128, Nn / 128), 256, 0, stream>>>(x, w, sq, W1);
  k_count<<<Ee / 256, 256, 0, stream>>>(src, dstv, degi, degrow);
  k_dis<<<Nn / 256, 256, 0, stream>>>(degi, dis, wmax);
  k_fill_ell<<<(Ee + Nn + 255) / 256, 256, 0, stream>>>(src, dstv, dis, slotcnt, ell);

  // pass 1: kgg1 = APPNP(K) -> out (row-major)
  k_appnp<1><<<Nn / CT, TPB, Nn * sizeof(float4), stream>>>(W1, out, ell, wmax, nullptr);
  // pass 2: in-place on out: reads kgg1 rows, writes final (kgg2^T, diag-scaled)
  k_appnp<2><<<Nn / CT, TPB, Nn * sizeof(float4), stream>>>(out, out, ell, wmax, degrow);
}